// Round 4
// baseline (135.452 us; speedup 1.0000x reference)
//
#include <hip/hip_runtime.h>

#define PP 16384
#define SQH 0.70710678118654752440f  // sqrt(0.5)

typedef unsigned int u32;
typedef unsigned short u16;
typedef __attribute__((ext_vector_type(8))) short bfrag;    // 8 bf16
typedef __attribute__((ext_vector_type(4))) float ffrag;    // 16x16 C/D
typedef __attribute__((ext_vector_type(16))) float ffrag16; // 32x32 C/D
typedef __attribute__((ext_vector_type(4))) float f4;

union BU { bfrag v; uint4 u; };

__device__ __forceinline__ u32 pk2(float a, float b) {
  u32 ua = __float_as_uint(a), ub = __float_as_uint(b);
  return ((ua + 0x8000u) >> 16) | ((ub + 0x8000u) & 0xffff0000u);
}

// ---- workspace layout (16 B units) ----
// [0, XT_F4)           xT: (P+1, 8, 16) f32  -- transposed in_pc + zero pad row
// [XT_F4, +1152)       WB: phase-2 conv-weight B-frags [2][9][64] uint4
// [XT_F4+1152, +128)   WR: residual B-frags [2][64] uint4
#define XT_F4 ((PP + 1) * 32)   // 524320 f4 units

__global__ void prep_kernel(const float* __restrict__ in_pc,
                            const float* __restrict__ weights,
                            const float* __restrict__ weight_res,
                            float* __restrict__ ws) {
  int gid = blockIdx.x * 256 + threadIdx.x;
  if (gid < XT_F4) {
    int i4 = gid & 3, b = (gid >> 2) & 7, p = gid >> 5;
    f4 v = {0.f, 0.f, 0.f, 0.f};
    if (p < PP) v = *(const f4*)(in_pc + ((size_t)b * PP + p) * 16 + i4 * 4);
    *(f4*)(ws + (size_t)gid * 4) = v;   // write-coalesced
    return;
  }
  int e = gid - XT_F4;
  if (e < 1152) {  // WB frag (nt, ks, l): B[k=ks*32+(l>>4)*8+j][n=nt*16+(l&15)]
    int nt = e / 576, rem = e - nt * 576;
    int ks = rem >> 6, l = rem & 63;
    int quad = l >> 4, n = l & 15;
    int k0 = ks * 32 + quad * 8;
    uint4 pkd = make_uint4(0u, 0u, 0u, 0u);
    if (k0 < 272) {
      int w = k0 >> 4, i0 = k0 & 15;
      const float* src = weights + w * 512 + (nt * 16 + n) * 16 + i0;
      f4 lo = *(const f4*)src;
      f4 hi = *(const f4*)(src + 4);
      pkd = make_uint4(pk2(lo.x, lo.y), pk2(lo.z, lo.w), pk2(hi.x, hi.y), pk2(hi.z, hi.w));
    }
    *(uint4*)(ws + (size_t)(XT_F4 + e) * 4) = pkd;
  } else if (e < 1280) {  // WR frag
    int l2 = e - 1152, nt = l2 >> 6, l = l2 & 63;
    int quad = l >> 4, n = l & 15;
    uint4 pkd = make_uint4(0u, 0u, 0u, 0u);
    if (quad < 2) {
      const float* src = weight_res + (nt * 16 + n) * 16 + quad * 8;
      f4 lo = *(const f4*)src;
      f4 hi = *(const f4*)(src + 4);
      pkd = make_uint4(pk2(lo.x, lo.y), pk2(lo.z, lo.w), pk2(hi.x, hi.y), pk2(hi.z, hi.w));
    }
    *(uint4*)(ws + (size_t)(XT_F4 + e) * 4) = pkd;
  }
}

// Main: 1024 blocks x 4 waves; each wave: 2 pairs (4 points), zero barriers.
// Per point: phase1 = 4x mfma_32x32x16 (A = gathered X^T bf16, B = ww bf16),
//            C -> Abuf (LDS) in phase-2 A-frag layout (row stride 296 u16).
// Per pair:  phase2 = 18x mfma_16x16x32 + 2 residual MFMAs + bias/ELU/mix.
__global__ __launch_bounds__(256, 4) void pconv_main(
    const float* __restrict__ ws,        // xT + WB + WR
    const float* __restrict__ bias,      // (P, 32) f32
    const float* __restrict__ w_weights, // (P, 16, 17) f32
    const int*  __restrict__ nidg,       // (P, 16) i32
    float* __restrict__ out)             // (8, P, 32) f32
{
  __shared__ __attribute__((aligned(16))) u16 Abuf[4 * 16 * 296];  // 37888 B

  const float* __restrict__ xT = ws;
  const uint4* __restrict__ WB = (const uint4*)(ws + (size_t)XT_F4 * 4);
  const uint4* __restrict__ WR = WB + 1152;

  const int tid = threadIdx.x;
  const int wid = __builtin_amdgcn_readfirstlane(tid >> 6);
  const int lane = tid & 63;
  const int lo16 = lane & 15, quad = lane >> 4;   // 16x16 MFMA role
  const int col = lane & 31, h = lane >> 5;       // 32x32 MFMA role
  u16* __restrict__ Aw = Abuf + wid * (16 * 296);

  // zero the K-tail [272,288) of all 16 rows, once (Abuf reused across pairs)
  {
    int r = lane >> 2, c = lane & 3;
    *(uint2*)(Aw + r * 296 + 272 + c * 4) = make_uint2(0u, 0u);
  }
  // hoist residual B-frags (stationary)
  BU rb0, rb1;
  rb0.u = WR[lane];
  rb1.u = WR[64 + lane];

  const int gw = blockIdx.x * 4 + wid;
  const int voff_g = (col >> 4) * 16 + (col & 15);  // gather voffset base (f32 units)

  for (int it = 0; it < 2; ++it) {
    const int pair = gw * 2 + it;
    const int p0 = pair * 2;

    // ---------------- phase 1: two points -> Abuf ----------------
#pragma unroll
    for (int pt = 0; pt < 2; ++pt) {
      const int p = p0 + pt;
      const int* __restrict__ nidp = nidg + p * 16;
      int nid[16];
#pragma unroll
      for (int m = 0; m < 16; ++m) nid[m] = nidp[m];  // uniform -> s_loads

      // B-frag: B[k=m][col=w] = ww[p, m, w]; w>=17 -> 0
      BU bb;
      {
        float v[8];
#pragma unroll
        for (int idx = 0; idx < 8; ++idx) {
          int m = h * 8 + idx;
          v[idx] = (col < 17) ? w_weights[(size_t)p * 272 + m * 17 + col] : 0.f;
        }
        bb.u = make_uint4(pk2(v[0], v[1]), pk2(v[2], v[3]), pk2(v[4], v[5]), pk2(v[6], v[7]));
      }

#pragma unroll
      for (int t = 0; t < 4; ++t) {
        // A[row=col][k=m=h*8+idx] = xT[nid[m]*128 + (col>>4)*16 + (col&15) + t*32]
        float v[8];
#pragma unroll
        for (int idx = 0; idx < 8; ++idx) {
          int m = h * 8 + idx;
          v[idx] = xT[(size_t)nid[m] * 128 + voff_g + t * 32];
        }
        BU aa;
        aa.u = make_uint4(pk2(v[0], v[1]), pk2(v[2], v[3]), pk2(v[4], v[5]), pk2(v[6], v[7]));
        ffrag16 c = {};
        c = __builtin_amdgcn_mfma_f32_32x32x16_bf16(aa.v, bb.v, c, 0, 0, 0);
        // C[row=(b,i)][col=w] -> A2[r=pt*8+b][k=w*16+i], 4 bf16 per reg-quad
        if (col < 17) {
#pragma unroll
          for (int q = 0; q < 4; ++q) {
            int r = pt * 8 + 2 * t + (q >> 1);
            int i0 = 4 * h + 8 * (q & 1);
            u16* dst = Aw + r * 296 + col * 16 + i0;
            *(uint2*)dst = make_uint2(pk2(c[4 * q + 0], c[4 * q + 1]),
                                      pk2(c[4 * q + 2], c[4 * q + 3]));
          }
        }
      }
    }

    // ---------------- phase 2 ----------------
    ffrag acc0 = {0.f, 0.f, 0.f, 0.f}, acc1 = {0.f, 0.f, 0.f, 0.f};
#pragma unroll
    for (int ks = 0; ks < 9; ++ks) {
      bfrag af = *(const bfrag*)(Aw + lo16 * 296 + ks * 32 + quad * 8);
      BU b0, b1;
      b0.u = WB[ks * 64 + lane];
      b1.u = WB[576 + ks * 64 + lane];
      acc0 = __builtin_amdgcn_mfma_f32_16x16x32_bf16(af, b0.v, acc0, 0, 0, 0);
      acc1 = __builtin_amdgcn_mfma_f32_16x16x32_bf16(af, b1.v, acc1, 0, 0, 0);
    }
    // residual: self rows from xT (p < P always)
    const int p_r = p0 + (lo16 >> 3), b_r = lo16 & 7;
    BU su;
    su.u = make_uint4(0u, 0u, 0u, 0u);
    if (quad < 2) {
      const float* sp = xT + (size_t)p_r * 128 + b_r * 16 + quad * 8;
      f4 lo = *(const f4*)sp;
      f4 hi = *(const f4*)(sp + 4);
      su.u = make_uint4(pk2(lo.x, lo.y), pk2(lo.z, lo.w), pk2(hi.x, hi.y), pk2(hi.z, hi.w));
    }
    ffrag rz = {0.f, 0.f, 0.f, 0.f};
    ffrag res0 = __builtin_amdgcn_mfma_f32_16x16x32_bf16(su.v, rb0.v, rz, 0, 0, 0);
    ffrag res1 = __builtin_amdgcn_mfma_f32_16x16x32_bf16(su.v, rb1.v, rz, 0, 0, 0);

    // ---------------- epilogue ----------------
#pragma unroll
    for (int j = 0; j < 4; ++j) {
      int r = quad * 4 + j;
      int p_e = p0 + (r >> 3), b_e = r & 7;
      size_t obase = ((size_t)b_e * PP + p_e) * 32;
      float c0 = acc0[j] + bias[(size_t)p_e * 32 + lo16];
      float c1 = acc1[j] + bias[(size_t)p_e * 32 + 16 + lo16];
      float e0 = c0 > 0.f ? c0 : (__expf(c0) - 1.f);
      float e1 = c1 > 0.f ? c1 : (__expf(c1) - 1.f);
      out[obase + lo16]      = SQH * e0 + SQH * res0[j];
      out[obase + 16 + lo16] = SQH * e1 + SQH * res1[j];
    }
  }
}

extern "C" void kernel_launch(void* const* d_in, const int* in_sizes, int n_in,
                              void* d_out, int out_size, void* d_ws, size_t ws_size,
                              hipStream_t stream) {
  const float* in_pc       = (const float*)d_in[0];
  const float* weights     = (const float*)d_in[1];
  const float* bias        = (const float*)d_in[2];
  const float* w_weights   = (const float*)d_in[3];
  const float* weight_res  = (const float*)d_in[4];
  const int*   neighbor_id = (const int*)d_in[5];
  float* out = (float*)d_out;
  float* ws = (float*)d_ws;  // needs ~8.41 MB

  hipLaunchKernelGGL(prep_kernel, dim3((XT_F4 + 1280 + 255) / 256), dim3(256), 0, stream,
                     in_pc, weights, weight_res, ws);
  hipLaunchKernelGGL(pconv_main, dim3(1024), dim3(256), 0, stream,
                     ws, bias, w_weights, neighbor_id, out);
}

// Round 5
// 107.398 us; speedup vs baseline: 1.2612x; 1.2612x over previous
//
#include <hip/hip_runtime.h>

#define PP 16384
#define SQH 0.70710678118654752440f  // sqrt(0.5)

typedef unsigned int u32;
typedef unsigned short u16;
typedef __attribute__((ext_vector_type(8))) short bfrag;    // 8 bf16
typedef __attribute__((ext_vector_type(4))) float ffrag;    // 16x16 C/D
typedef __attribute__((ext_vector_type(16))) float ffrag16; // 32x32 C/D
typedef __attribute__((ext_vector_type(4))) float f4;
typedef __attribute__((ext_vector_type(2))) float f2;

union BU { bfrag v; uint4 u; };

__device__ __forceinline__ u32 pk2(float a, float b) {
  u32 ua = __float_as_uint(a), ub = __float_as_uint(b);
  return ((ua + 0x8000u) >> 16) | ((ub + 0x8000u) & 0xffff0000u);
}

// ---- workspace layout (bytes) ----
// [0, XTB_B)        xTb: (P+1, 8, 16) bf16   -- transposed in_pc, zero pad row
// [XTB_B, +16 MB)   WW1: phase-1 ww B-frags, per point 64 lanes x uint4
// [WB_B, +18432)    WB : phase-2 conv-weight B-frags [2][9][64] uint4
// [WR_B, +2048)     WR : residual B-frags [2][64] uint4
#define XTB_U16 ((PP + 1) * 128)
#define XTB_B   (XTB_U16 * 2)            // 4,194,560
#define WW1_B   (XTB_B)                  // start of WW1
#define WB_B    (XTB_B + PP * 1024)      // 20,971,776
#define WR_B    (WB_B + 18432)
#define XDW     ((PP + 1) * 64)          // xTb dword count
#define NW1     (PP * 64)                // WW1 uint4 count

__global__ void prep_kernel(const float* __restrict__ in_pc,
                            const float* __restrict__ weights,
                            const float* __restrict__ w_weights,
                            const float* __restrict__ weight_res,
                            u32* __restrict__ ws) {
  int gid = blockIdx.x * 256 + threadIdx.x;
  if (gid < XDW) {  // xTb: dword = 2 bf16; p = gid>>6, c = gid&63 -> b=c>>3, i0=(c&7)*2
    int p = gid >> 6, c = gid & 63;
    u32 dw = 0u;
    if (p < PP) {
      int b = c >> 3, i0 = (c & 7) * 2;
      const float* s = in_pc + ((size_t)b * PP + p) * 16 + i0;
      dw = pk2(s[0], s[1]);
    }
    ws[gid] = dw;
    return;
  }
  int e = gid - XDW;
  if (e < NW1) {  // WW1 frag: point p, lane l: B[k=m=h*8+idx][n=col] = ww[p][m][col]
    int p = e >> 6, l = e & 63;
    int h = l >> 5, col = l & 31;
    float v[8];
#pragma unroll
    for (int idx = 0; idx < 8; ++idx)
      v[idx] = (col < 17) ? w_weights[(size_t)p * 272 + (h * 8 + idx) * 17 + col] : 0.f;
    uint4 pkd = make_uint4(pk2(v[0], v[1]), pk2(v[2], v[3]), pk2(v[4], v[5]), pk2(v[6], v[7]));
    *(uint4*)((char*)ws + WW1_B + (size_t)e * 16) = pkd;
    return;
  }
  e -= NW1;
  if (e < 1152) {  // WB frag (nt, ks, l): B[k=ks*32+(l>>4)*8+j][n=nt*16+(l&15)]
    int nt = e / 576, rem = e - nt * 576;
    int ks = rem >> 6, l = rem & 63;
    int quad = l >> 4, n = l & 15;
    int k0 = ks * 32 + quad * 8;
    uint4 pkd = make_uint4(0u, 0u, 0u, 0u);
    if (k0 < 272) {
      int w = k0 >> 4, i0 = k0 & 15;
      const float* src = weights + w * 512 + (nt * 16 + n) * 16 + i0;
      f4 lo = *(const f4*)src;
      f4 hi = *(const f4*)(src + 4);
      pkd = make_uint4(pk2(lo.x, lo.y), pk2(lo.z, lo.w), pk2(hi.x, hi.y), pk2(hi.z, hi.w));
    }
    *(uint4*)((char*)ws + WB_B + (size_t)e * 16) = pkd;
  } else if (e < 1280) {  // WR frag
    int l2 = e - 1152, nt = l2 >> 6, l = l2 & 63;
    int quad = l >> 4, n = l & 15;
    uint4 pkd = make_uint4(0u, 0u, 0u, 0u);
    if (quad < 2) {
      const float* src = weight_res + (nt * 16 + n) * 16 + quad * 8;
      f4 lo = *(const f4*)src;
      f4 hi = *(const f4*)(src + 4);
      pkd = make_uint4(pk2(lo.x, lo.y), pk2(lo.z, lo.w), pk2(hi.x, hi.y), pk2(hi.z, hi.w));
    }
    *(uint4*)((char*)ws + WR_B + (size_t)(e - 1152) * 16) = pkd;
  }
}

// Main: 2048 blocks x 4 waves; ONE point-pair per wave, zero barriers.
// Phase1 per point: 32 bf16 scatter-gathers -> A-frags, pre-packed ww B-frag,
//   4x mfma_32x32x16, C packed bf16 -> per-wave LDS A2[16][296].
// Phase2: 9x2 mfma_16x16x32 + 2 residual MFMAs.
// Epilogue: bias/ELU/mix -> LDS f32 [16][40] transpose -> full-line dwordx4 stores.
__global__ __launch_bounds__(256, 4) void pconv_main(
    const u32* __restrict__ ws,
    const float* __restrict__ bias,      // (P, 32) f32
    const int*  __restrict__ nidg,       // (P, 16) i32
    float* __restrict__ out)             // (8, P, 32) f32
{
  __shared__ __attribute__((aligned(16))) u16 Abuf[4 * 16 * 296];  // 37888 B

  const u16*  __restrict__ xTb = (const u16*)ws;
  const uint4* __restrict__ WW1 = (const uint4*)((const char*)ws + WW1_B);
  const uint4* __restrict__ WB  = (const uint4*)((const char*)ws + WB_B);
  const uint4* __restrict__ WR  = (const uint4*)((const char*)ws + WR_B);

  const int tid = threadIdx.x;
  const int wid = __builtin_amdgcn_readfirstlane(tid >> 6);
  const int lane = tid & 63;
  const int lo16 = lane & 15, quad = lane >> 4;   // 16x16 MFMA role
  const int col = lane & 31, h = lane >> 5;       // 32x32 MFMA role
  u16* __restrict__ Aw = Abuf + wid * (16 * 296);

  const int pair = blockIdx.x * 4 + wid;
  const int p0 = pair * 2;

  // zero K-tail [272,288) of all 16 A2 rows
  {
    int r = lane >> 2, c = lane & 3;
    *(uint2*)(Aw + r * 296 + 272 + c * 4) = make_uint2(0u, 0u);
  }

  // ---- issue everything independent up front ----
  const int* __restrict__ nid0p = nidg + p0 * 16;
  const int* __restrict__ nid1p = nidg + (p0 + 1) * 16;
  int nid0[16], nid1[16];
#pragma unroll
  for (int m = 0; m < 16; ++m) nid0[m] = nid0p[m];  // uniform -> s_load
#pragma unroll
  for (int m = 0; m < 16; ++m) nid1[m] = nid1p[m];

  BU bb0, bb1;
  bb0.u = WW1[(size_t)p0 * 64 + lane];
  bb1.u = WW1[(size_t)(p0 + 1) * 64 + lane];

  const int voffb = (col >> 4) * 16 + (col & 15);  // u16 units within a row

  // gathers: a[t][j] = bf16 pair (m=h*8+2j, h*8+2j+1) at (b=2t+(col>>4), i=col&15)
  u32 a0[4][4], a1[4][4];
#pragma unroll
  for (int j = 0; j < 4; ++j) {
    const u16* q0 = xTb + (size_t)nid0[h * 8 + 2 * j] * 128 + voffb;
    const u16* q1 = xTb + (size_t)nid0[h * 8 + 2 * j + 1] * 128 + voffb;
#pragma unroll
    for (int t = 0; t < 4; ++t)
      a0[t][j] = (u32)q0[t * 32] | ((u32)q1[t * 32] << 16);
  }
#pragma unroll
  for (int j = 0; j < 4; ++j) {
    const u16* q0 = xTb + (size_t)nid1[h * 8 + 2 * j] * 128 + voffb;
    const u16* q1 = xTb + (size_t)nid1[h * 8 + 2 * j + 1] * 128 + voffb;
#pragma unroll
    for (int t = 0; t < 4; ++t)
      a1[t][j] = (u32)q0[t * 32] | ((u32)q1[t * 32] << 16);
  }

  // ---- phase 1: two points -> A2 in LDS ----
#pragma unroll
  for (int pt = 0; pt < 2; ++pt) {
    const u32 (&ad)[4][4] = pt ? a1 : a0;
    BU bb = pt ? bb1 : bb0;
#pragma unroll
    for (int t = 0; t < 4; ++t) {
      BU aa;
      aa.u = make_uint4(ad[t][0], ad[t][1], ad[t][2], ad[t][3]);
      ffrag16 c = {};
      c = __builtin_amdgcn_mfma_f32_32x32x16_bf16(aa.v, bb.v, c, 0, 0, 0);
      if (col < 17) {
#pragma unroll
        for (int q = 0; q < 4; ++q) {
          int r = pt * 8 + 2 * t + (q >> 1);
          int i0 = 4 * h + 8 * (q & 1);
          u16* dst = Aw + r * 296 + col * 16 + i0;
          *(uint2*)dst = make_uint2(pk2(c[4 * q + 0], c[4 * q + 1]),
                                    pk2(c[4 * q + 2], c[4 * q + 3]));
        }
      }
    }
  }

  // ---- phase 2: C[16x32] = A2[16x288] * W ----
  ffrag acc0 = {0.f, 0.f, 0.f, 0.f}, acc1 = {0.f, 0.f, 0.f, 0.f};
#pragma unroll
  for (int ks = 0; ks < 9; ++ks) {
    bfrag af = *(const bfrag*)(Aw + lo16 * 296 + ks * 32 + quad * 8);
    BU b0, b1;
    b0.u = WB[ks * 64 + lane];
    b1.u = WB[576 + ks * 64 + lane];
    acc0 = __builtin_amdgcn_mfma_f32_16x16x32_bf16(af, b0.v, acc0, 0, 0, 0);
    acc1 = __builtin_amdgcn_mfma_f32_16x16x32_bf16(af, b1.v, acc1, 0, 0, 0);
  }
  // residual: self rows straight from bf16 xTb
  {
    const int p_r = p0 + (lo16 >> 3), b_r = lo16 & 7;
    BU su;
    su.u = make_uint4(0u, 0u, 0u, 0u);
    if (quad < 2)
      su.u = *(const uint4*)(xTb + (size_t)p_r * 128 + b_r * 16 + quad * 8);
    BU rb0, rb1;
    rb0.u = WR[lane];
    rb1.u = WR[64 + lane];
    ffrag rz = {0.f, 0.f, 0.f, 0.f};
    ffrag res0 = __builtin_amdgcn_mfma_f32_16x16x32_bf16(su.v, rb0.v, rz, 0, 0, 0);
    ffrag res1 = __builtin_amdgcn_mfma_f32_16x16x32_bf16(su.v, rb1.v, rz, 0, 0, 0);

    // ---- epilogue: compute, stage f32 in LDS [16][40], store full lines ----
    float* Ef = (float*)Aw;
#pragma unroll
    for (int j = 0; j < 4; ++j) {
      int r = quad * 4 + j;
      int p_e = p0 + (r >> 3);
      float c0 = acc0[j] + bias[(size_t)p_e * 32 + lo16];
      float c1 = acc1[j] + bias[(size_t)p_e * 32 + 16 + lo16];
      float e0 = c0 > 0.f ? c0 : (__expf(c0) - 1.f);
      float e1 = c1 > 0.f ? c1 : (__expf(c1) - 1.f);
      Ef[r * 40 + lo16]      = SQH * e0 + SQH * res0[j];
      Ef[r * 40 + 16 + lo16] = SQH * e1 + SQH * res1[j];
    }
#pragma unroll
    for (int k = 0; k < 2; ++k) {
      int rr = (lane >> 3) + 8 * k;   // A2/C row = (pt, b)
      int cc = lane & 7;
      f4 v = *(const f4*)(Ef + rr * 40 + cc * 4);
      int p_s = p0 + (rr >> 3), b_s = rr & 7;
      *(f4*)(out + ((size_t)b_s * PP + p_s) * 32 + cc * 4) = v;  // 8 full lines/instr
    }
  }
}

extern "C" void kernel_launch(void* const* d_in, const int* in_sizes, int n_in,
                              void* d_out, int out_size, void* d_ws, size_t ws_size,
                              hipStream_t stream) {
  const float* in_pc       = (const float*)d_in[0];
  const float* weights     = (const float*)d_in[1];
  const float* bias        = (const float*)d_in[2];
  const float* w_weights   = (const float*)d_in[3];
  const float* weight_res  = (const float*)d_in[4];
  const int*   neighbor_id = (const int*)d_in[5];
  float* out = (float*)d_out;
  u32* ws = (u32*)d_ws;  // needs ~21 MB

  int prep_threads = XDW + NW1 + 1280;
  hipLaunchKernelGGL(prep_kernel, dim3((prep_threads + 255) / 256), dim3(256), 0, stream,
                     in_pc, weights, w_weights, weight_res, ws);
  // 2048 blocks x 4 waves x 1 pair x 2 points = 16384 points
  hipLaunchKernelGGL(pconv_main, dim3(2048), dim3(256), 0, stream,
                     ws, bias, neighbor_id, out);
}